// Round 7
// baseline (326.460 us; speedup 1.0000x reference)
//
#include <hip/hip_runtime.h>

typedef short short8 __attribute__((ext_vector_type(8)));
typedef short short4v __attribute__((ext_vector_type(4)));
typedef float f32x4 __attribute__((ext_vector_type(4)));
typedef unsigned short u16;
typedef u16 ushort4v __attribute__((ext_vector_type(4)));

__device__ inline u16 f2bf(float f){
  unsigned int u = __builtin_bit_cast(unsigned int, f);
  u = (u + 0x7fffu + ((u >> 16) & 1u)) >> 16;
  return (u16)u;
}

__device__ inline short8 cat8(short4v a, short4v b){
  short8 r;
  r[0]=a[0]; r[1]=a[1]; r[2]=a[2]; r[3]=a[3];
  r[4]=b[0]; r[5]=b[1]; r[6]=b[2]; r[7]=b[3];
  return r;
}

// async global->LDS, 16B per lane. lds dest = wave-uniform base + lane*16.
__device__ inline void gload_lds16(const void* g, unsigned lds_addr){
  __builtin_amdgcn_global_load_lds((__attribute__((address_space(1))) void*)(uintptr_t)g,
                                   (__attribute__((address_space(3))) void*)(uintptr_t)lds_addr,
                                   16, 0, 0);
}

// ---------------- f32 -> bf16 convert (vectorized) ----------------
__global__ void cvt_bf16(const float* __restrict__ in, u16* __restrict__ out, int n4){
  int stride = gridDim.x * blockDim.x;
  for (int i = blockIdx.x * blockDim.x + threadIdx.x; i < n4; i += stride){
    float4 v = ((const float4*)in)[i];
    ushort4v r = { f2bf(v.x), f2bf(v.y), f2bf(v.z), f2bf(v.w) };
    ((ushort4v*)out)[i] = r;
  }
}

// ---------------- bf16 GEMM: C[M][N] = A[M][K] * B[N][K]^T ----------------
// m97 structure (r4 champion, 862 TF): 128x128 tile, BK=64, 256 thr,
// global_load_lds(16B) into linear LDS, XOR-swizzled source+read (0 conflicts),
// multi-block co-residency does the pipelining. + bijective XCD swizzle.
template<int OUT_BF16>
__global__ __launch_bounds__(256) void gemm_bt(const u16* __restrict__ A, const u16* __restrict__ B,
                                               void* __restrict__ Cv, int M, int N, int K){
  __shared__ u16 As[128 * 64];
  __shared__ u16 Bs[128 * 64];
  const int tid  = threadIdx.x;
  const int wave = tid >> 6, lane = tid & 63;
  const int lr = lane & 15, lg = lane >> 4;
  const int wm = wave >> 1, wn = wave & 1;

  // XCD-aware block swizzle (bijective: grid sizes are multiples of 8)
  const int bid = blockIdx.y * gridDim.x + blockIdx.x;
  const int cpx = (gridDim.x * gridDim.y) >> 3;
  const int swz = (bid & 7) * cpx + (bid >> 3);
  const long bm = (swz & 31) * 128L;          // gridDim.x == 32 for both GEMMs
  const long bn = (swz >> 5) * 128L;

  const unsigned asb = (unsigned)(uintptr_t)As;
  const unsigned bsb = (unsigned)(uintptr_t)Bs;

  const int  srow = wave * 32 + (lane >> 3);
  const int  scol = ((lane & 7) ^ (lane >> 3)) * 8;
  const u16* aptr = A + (bm + srow) * (long)K + scol;
  const u16* bptr = B + (bn + srow) * (long)K + scol;
  const unsigned sdst = (unsigned)(wave * 4096);

  f32x4 acc[4][4] = {};
  for (int k0 = 0; k0 < K; k0 += 64){
    #pragma unroll
    for (int c = 0; c < 4; c++){
      gload_lds16(aptr + (size_t)(8 * c) * K + k0, asb + sdst + 1024u * c);
      gload_lds16(bptr + (size_t)(8 * c) * K + k0, bsb + sdst + 1024u * c);
    }
    __syncthreads();
    #pragma unroll
    for (int kk = 0; kk < 2; kk++){
      short8 af[4], bfr[4];
      #pragma unroll
      for (int m = 0; m < 4; m++){
        int row = wm * 64 + m * 16 + lr;
        int phys = (kk * 4 + lg) ^ (row & 7);
        af[m] = *(const short8*)&As[row * 64 + phys * 8];
      }
      #pragma unroll
      for (int n = 0; n < 4; n++){
        int row = wn * 64 + n * 16 + lr;
        int phys = (kk * 4 + lg) ^ (row & 7);
        bfr[n] = *(const short8*)&Bs[row * 64 + phys * 8];
      }
      #pragma unroll
      for (int m = 0; m < 4; m++)
        #pragma unroll
        for (int n = 0; n < 4; n++)
          acc[m][n] = __builtin_amdgcn_mfma_f32_16x16x32_bf16(af[m], bfr[n], acc[m][n], 0, 0, 0);
    }
    __syncthreads();
  }
  #pragma unroll
  for (int m = 0; m < 4; m++){
    #pragma unroll
    for (int n = 0; n < 4; n++){
      #pragma unroll
      for (int r = 0; r < 4; r++){
        long row = bm + wm*64 + m*16 + lg*4 + r;
        long col = bn + wn*64 + n*16 + lr;
        float v = acc[m][n][r];
        if (OUT_BF16) ((u16*)Cv)[row * (long)N + col] = f2bf(v);
        else          ((float*)Cv)[row * (long)N + col] = v;
      }
    }
  }
}

// ---------------- causal flash attention ----------------
// 256 thr = 4 waves; Q-tile 128 (32 q-rows/wave as 2 frags); KV-tile 64.
// LDS 53 KB -> 2 blocks/CU: independent blocks fill each other's
// softmax/staging stalls. Paired q-tiles (15-pr, pr) -> uniform work.
__global__ __launch_bounds__(256, 2) void attn_fwd(const u16* __restrict__ qkv, u16* __restrict__ out){
  const int T = 2048, D3 = 6144, D = 2048, HD = 128;
  const int bh = blockIdx.x;
  const int pr = blockIdx.y;            // 0..7
  const int b = bh >> 4, h = bh & 15;
  const int tid = threadIdx.x, wave = tid >> 6, lane = tid & 63;
  const int lr = lane & 15, lg = lane >> 4;

  __shared__ u16 Klds[64][136];
  __shared__ u16 Vlds[64][136];
  __shared__ u16 Plds[4][32][72];

  const size_t base = (size_t)b * T * D3;
  const unsigned vtr = (unsigned)(uintptr_t)&Vlds[(lane >> 4) * 8 + ((lane >> 2) & 3)][(lane & 3) * 4];

  // staging: 256 thr, 4 sweeps: row = (tid>>4) + 16c, col = (tid&15)*8
  const int srow = tid >> 4;
  const int scol = (tid & 15) * 8;
  const u16* kgp = qkv + base + (size_t)srow * D3 + D + h * HD + scol;
  const u16* vgp = kgp + D;

  for (int half = 0; half < 2; half++){
    const int qt = half ? pr : (15 - pr);
    const int q0 = qt * 128;
    const int q0w = q0 + wave * 32;

    short8 qf[2][4];
    #pragma unroll
    for (int qr = 0; qr < 2; qr++){
      const u16* qrow = qkv + base + (size_t)(q0w + qr*16 + lr) * D3 + h * HD;
      #pragma unroll
      for (int kk = 0; kk < 4; kk++)
        qf[qr][kk] = *(const short8*)(qrow + kk*32 + lg*8);
    }

    f32x4 o[8][2] = {};
    float mrow[2][4], lrw[2][4];
    #pragma unroll
    for (int qr = 0; qr < 2; qr++)
      #pragma unroll
      for (int r = 0; r < 4; r++){ mrow[qr][r] = -1e30f; lrw[qr][r] = 0.f; }

    const int ntiles = (q0 + 128) >> 6;
    short8 kreg[4], vreg[4];
    #pragma unroll
    for (int c = 0; c < 4; c++){
      kreg[c] = *(const short8*)(kgp + (size_t)(16 * c) * D3);
      vreg[c] = *(const short8*)(vgp + (size_t)(16 * c) * D3);
    }

    for (int t = 0; t < ntiles; t++){
      const int k0 = t * 64;
      __syncthreads();                       // prior tile's LDS reads done
      #pragma unroll
      for (int c = 0; c < 4; c++){
        *(short8*)&Klds[srow + 16*c][scol] = kreg[c];
        *(short8*)&Vlds[srow + 16*c][scol] = vreg[c];
      }
      __syncthreads();                       // tile staged
      if (t + 1 < ntiles){                   // T14: issue next loads early
        const u16* kn = kgp + (size_t)(k0 + 64) * D3;
        const u16* vn = vgp + (size_t)(k0 + 64) * D3;
        #pragma unroll
        for (int c = 0; c < 4; c++){
          kreg[c] = *(const short8*)(kn + (size_t)(16 * c) * D3);
          vreg[c] = *(const short8*)(vn + (size_t)(16 * c) * D3);
        }
      }

      if (k0 <= q0w + 31){
        // ---- S = Q K^T (2 q-frags share each K fragment) ----
        f32x4 s[2][4] = {};
        #pragma unroll
        for (int kh = 0; kh < 4; kh++){
          #pragma unroll
          for (int kk = 0; kk < 4; kk++){
            short8 kfrag = *(const short8*)&Klds[kh*16 + lr][kk*32 + lg*8];
            s[0][kh] = __builtin_amdgcn_mfma_f32_16x16x32_bf16(qf[0][kk], kfrag, s[0][kh], 0, 0, 0);
            s[1][kh] = __builtin_amdgcn_mfma_f32_16x16x32_bf16(qf[1][kk], kfrag, s[1][kh], 0, 0, 0);
          }
        }
        const float scale = 0.08838834764831845f; // 1/sqrt(128)
        const bool need_mask = (k0 + 63 > q0w);
        #pragma unroll
        for (int kh = 0; kh < 4; kh++){
          int key = k0 + kh*16 + lr;
          #pragma unroll
          for (int qr = 0; qr < 2; qr++){
            #pragma unroll
            for (int r = 0; r < 4; r++){
              float v = s[qr][kh][r] * scale;
              if (need_mask && key > q0w + qr*16 + lg*4 + r) v = -1e30f;
              s[qr][kh][r] = v;
            }
          }
        }
        // ---- online softmax (row = lg*4+r per 16-lane group, col = lr) ----
        float fs[2][4];
        #pragma unroll
        for (int qr = 0; qr < 2; qr++){
          #pragma unroll
          for (int r = 0; r < 4; r++){
            float mx = fmaxf(fmaxf(s[qr][0][r], s[qr][1][r]), fmaxf(s[qr][2][r], s[qr][3][r]));
            #pragma unroll
            for (int msk = 8; msk >= 1; msk >>= 1)
              mx = fmaxf(mx, __shfl_xor(mx, msk, 64));
            float mnew = fmaxf(mrow[qr][r], mx);
            float f = __expf(mrow[qr][r] - mnew);
            float p0 = __expf(s[qr][0][r] - mnew);
            float p1 = __expf(s[qr][1][r] - mnew);
            float p2 = __expf(s[qr][2][r] - mnew);
            float p3 = __expf(s[qr][3][r] - mnew);
            s[qr][0][r] = p0; s[qr][1][r] = p1; s[qr][2][r] = p2; s[qr][3][r] = p3;
            float rs = (p0 + p1) + (p2 + p3);
            #pragma unroll
            for (int msk = 8; msk >= 1; msk >>= 1)
              rs += __shfl_xor(rs, msk, 64);
            lrw[qr][r] = lrw[qr][r] * f + rs;
            mrow[qr][r] = mnew;
            fs[qr][r] = f;
          }
        }
        #pragma unroll
        for (int dt = 0; dt < 8; dt++)
          #pragma unroll
          for (int qr = 0; qr < 2; qr++)
            #pragma unroll
            for (int r = 0; r < 4; r++)
              o[dt][qr][r] *= fs[qr][r];
        // ---- P -> LDS (bf16) ----
        #pragma unroll
        for (int qr = 0; qr < 2; qr++)
          #pragma unroll
          for (int kh = 0; kh < 4; kh++)
            #pragma unroll
            for (int r = 0; r < 4; r++)
              Plds[wave][qr*16 + lg*4 + r][kh*16 + lr] = f2bf(s[qr][kh][r]);
        asm volatile("s_waitcnt lgkmcnt(0)" ::: "memory");
        __builtin_amdgcn_sched_barrier(0);
        short8 pf[2][2];
        #pragma unroll
        for (int qr = 0; qr < 2; qr++)
          #pragma unroll
          for (int kp2 = 0; kp2 < 2; kp2++)
            pf[qr][kp2] = *(const short8*)&Plds[wave][qr*16 + lr][kp2*32 + lg*8];
        asm volatile("s_waitcnt lgkmcnt(0)" ::: "memory");
        __builtin_amdgcn_sched_barrier(0);

        // ---- PV with pipelined hardware-transpose V reads ----
        short4v vf[2][2][2];
        #define TR4(BUF, PTR) \
          asm volatile("ds_read_b64_tr_b16 %0, %1"             : "=v"(vf[BUF][0][0]) : "v"(PTR)); \
          asm volatile("ds_read_b64_tr_b16 %0, %1 offset:1088" : "=v"(vf[BUF][0][1]) : "v"(PTR)); \
          asm volatile("ds_read_b64_tr_b16 %0, %1 offset:8704" : "=v"(vf[BUF][1][0]) : "v"(PTR)); \
          asm volatile("ds_read_b64_tr_b16 %0, %1 offset:9792" : "=v"(vf[BUF][1][1]) : "v"(PTR));
        TR4(0, vtr)
        #pragma unroll
        for (int dt = 0; dt < 8; dt++){
          if (dt < 7){
            unsigned pn = vtr + (unsigned)((dt + 1) * 32);
            TR4((dt + 1) & 1, pn)
            asm volatile("s_waitcnt lgkmcnt(4)" ::: "memory");
          } else {
            asm volatile("s_waitcnt lgkmcnt(0)" ::: "memory");
          }
          __builtin_amdgcn_sched_barrier(0);
          short8 v0 = cat8(vf[dt & 1][0][0], vf[dt & 1][0][1]);
          short8 v1 = cat8(vf[dt & 1][1][0], vf[dt & 1][1][1]);
          o[dt][0] = __builtin_amdgcn_mfma_f32_16x16x32_bf16(pf[0][0], v0, o[dt][0], 0, 0, 0);
          o[dt][1] = __builtin_amdgcn_mfma_f32_16x16x32_bf16(pf[1][0], v0, o[dt][1], 0, 0, 0);
          o[dt][0] = __builtin_amdgcn_mfma_f32_16x16x32_bf16(pf[0][1], v1, o[dt][0], 0, 0, 0);
          o[dt][1] = __builtin_amdgcn_mfma_f32_16x16x32_bf16(pf[1][1], v1, o[dt][1], 0, 0, 0);
        }
        #undef TR4
      }
    }
    // ---- epilogue ----
    #pragma unroll
    for (int qr = 0; qr < 2; qr++){
      float rl[4];
      #pragma unroll
      for (int r = 0; r < 4; r++) rl[r] = 1.0f / lrw[qr][r];
      #pragma unroll
      for (int dt = 0; dt < 8; dt++){
        #pragma unroll
        for (int r = 0; r < 4; r++){
          float v = o[dt][qr][r] * rl[r];
          int qa = q0w + qr*16 + lg*4 + r;
          out[(size_t)(b * T + qa) * D + h * HD + dt*16 + lr] = f2bf(v);
        }
      }
    }
  }
}

extern "C" void kernel_launch(void* const* d_in, const int* in_sizes, int n_in,
                              void* d_out, int out_size, void* d_ws, size_t ws_size,
                              hipStream_t stream) {
  const float* x    = (const float*)d_in[0];   // [2,2048,2048]
  const float* wqkv = (const float*)d_in[1];   // [6144,2048]
  const float* wout = (const float*)d_in[2];   // [2048,2048]
  float* out = (float*)d_out;                  // [2,2048,2048] f32

  u16* ws    = (u16*)d_ws;
  u16* xb    = ws;                    //  8,388,608 elems
  u16* wqkvb = xb + 8388608;          // 12,582,912 elems
  u16* qkvb  = wqkvb + 12582912;      // 25,165,824 elems
  u16* attnb = xb;                    // alias: x dead after GEMM1
  u16* woutb = wqkvb;                 // alias: wqkv dead after GEMM1

  cvt_bf16<<<2048, 256, 0, stream>>>(x,    xb,    8388608 / 4);
  cvt_bf16<<<2048, 256, 0, stream>>>(wqkv, wqkvb, 12582912 / 4);

  // qkv = x @ Wqkv^T : [4096][6144] bf16  (128^2 m97, 32x48 = 1536 blocks)
  gemm_bt<1><<<dim3(32, 48), 256, 0, stream>>>(xb, wqkvb, qkvb, 4096, 6144, 2048);

  cvt_bf16<<<2048, 256, 0, stream>>>(wout, woutb, 4194304 / 4);

  // attention: [4096][2048] bf16  (256 thr, 2 blocks/CU)
  attn_fwd<<<dim3(32, 8), 256, 0, stream>>>(qkvb, attnb);

  // y = attn @ Wout^T : [4096][2048] f32  (32x16 = 512 blocks)
  gemm_bt<0><<<dim3(32, 16), 256, 0, stream>>>(attnb, woutb, out, 4096, 2048, 2048);
}

// Round 8
// 293.403 us; speedup vs baseline: 1.1127x; 1.1127x over previous
//
#include <hip/hip_runtime.h>

typedef short short8 __attribute__((ext_vector_type(8)));
typedef short short4v __attribute__((ext_vector_type(4)));
typedef float f32x4 __attribute__((ext_vector_type(4)));
typedef unsigned short u16;
typedef u16 ushort4v __attribute__((ext_vector_type(4)));

__device__ inline u16 f2bf(float f){
  unsigned int u = __builtin_bit_cast(unsigned int, f);
  u = (u + 0x7fffu + ((u >> 16) & 1u)) >> 16;
  return (u16)u;
}

__device__ inline short8 cat8(short4v a, short4v b){
  short8 r;
  r[0]=a[0]; r[1]=a[1]; r[2]=a[2]; r[3]=a[3];
  r[4]=b[0]; r[5]=b[1]; r[6]=b[2]; r[7]=b[3];
  return r;
}

// async global->LDS, 16B per lane. lds dest = wave-uniform base + lane*16.
__device__ inline void gload_lds16(const void* g, unsigned lds_addr){
  __builtin_amdgcn_global_load_lds((__attribute__((address_space(1))) void*)(uintptr_t)g,
                                   (__attribute__((address_space(3))) void*)(uintptr_t)lds_addr,
                                   16, 0, 0);
}

// ---------------- f32 -> bf16 convert (vectorized) ----------------
__global__ void cvt_bf16(const float* __restrict__ in, u16* __restrict__ out, int n4){
  int stride = gridDim.x * blockDim.x;
  for (int i = blockIdx.x * blockDim.x + threadIdx.x; i < n4; i += stride){
    float4 v = ((const float4*)in)[i];
    ushort4v r = { f2bf(v.x), f2bf(v.y), f2bf(v.z), f2bf(v.w) };
    ((ushort4v*)out)[i] = r;
  }
}

// ---------------- bf16 GEMM: C[M][N] = A[M][K] * B[N][K]^T ----------------
// m97 structure: 128x128 tile, BK=64, 256 thr, global_load_lds(16B) into
// linear LDS, XOR-swizzled source+read (0 conflicts), co-residency pipelines.
template<int OUT_BF16>
__global__ __launch_bounds__(256) void gemm_bt(const u16* __restrict__ A, const u16* __restrict__ B,
                                               void* __restrict__ Cv, int M, int N, int K){
  __shared__ u16 As[128 * 64];
  __shared__ u16 Bs[128 * 64];
  const int tid  = threadIdx.x;
  const int wave = tid >> 6, lane = tid & 63;
  const int lr = lane & 15, lg = lane >> 4;
  const int wm = wave >> 1, wn = wave & 1;

  // XCD-aware block swizzle (bijective: grid sizes are multiples of 8)
  const int bid = blockIdx.y * gridDim.x + blockIdx.x;
  const int cpx = (gridDim.x * gridDim.y) >> 3;
  const int swz = (bid & 7) * cpx + (bid >> 3);
  const long bm = (swz & 31) * 128L;          // gridDim.x == 32 for both GEMMs
  const long bn = (swz >> 5) * 128L;

  const unsigned asb = (unsigned)(uintptr_t)As;
  const unsigned bsb = (unsigned)(uintptr_t)Bs;

  const int  srow = wave * 32 + (lane >> 3);
  const int  scol = ((lane & 7) ^ (lane >> 3)) * 8;
  const u16* aptr = A + (bm + srow) * (long)K + scol;
  const u16* bptr = B + (bn + srow) * (long)K + scol;
  const unsigned sdst = (unsigned)(wave * 4096);

  f32x4 acc[4][4] = {};
  for (int k0 = 0; k0 < K; k0 += 64){
    #pragma unroll
    for (int c = 0; c < 4; c++){
      gload_lds16(aptr + (size_t)(8 * c) * K + k0, asb + sdst + 1024u * c);
      gload_lds16(bptr + (size_t)(8 * c) * K + k0, bsb + sdst + 1024u * c);
    }
    __syncthreads();
    #pragma unroll
    for (int kk = 0; kk < 2; kk++){
      short8 af[4], bfr[4];
      #pragma unroll
      for (int m = 0; m < 4; m++){
        int row = wm * 64 + m * 16 + lr;
        int phys = (kk * 4 + lg) ^ (row & 7);
        af[m] = *(const short8*)&As[row * 64 + phys * 8];
      }
      #pragma unroll
      for (int n = 0; n < 4; n++){
        int row = wn * 64 + n * 16 + lr;
        int phys = (kk * 4 + lg) ^ (row & 7);
        bfr[n] = *(const short8*)&Bs[row * 64 + phys * 8];
      }
      #pragma unroll
      for (int m = 0; m < 4; m++)
        #pragma unroll
        for (int n = 0; n < 4; n++)
          acc[m][n] = __builtin_amdgcn_mfma_f32_16x16x32_bf16(af[m], bfr[n], acc[m][n], 0, 0, 0);
    }
    __syncthreads();
  }
  #pragma unroll
  for (int m = 0; m < 4; m++){
    #pragma unroll
    for (int n = 0; n < 4; n++){
      #pragma unroll
      for (int r = 0; r < 4; r++){
        long row = bm + wm*64 + m*16 + lg*4 + r;
        long col = bn + wn*64 + n*16 + lr;
        float v = acc[m][n][r];
        if (OUT_BF16) ((u16*)Cv)[row * (long)N + col] = f2bf(v);
        else          ((float*)Cv)[row * (long)N + col] = v;
      }
    }
  }
}

// ---------------- causal flash attention ----------------
// 256 thr = 4 waves x 16 q-rows (64-row q-subtile per half); KV-tile 64.
// Pair (31-p, p) over 32 subtiles -> uniform 33 KV-tiles/block.
// Grid 32 x 16 = 512 blocks = 2 blocks/CU (LDS 44KB): independent
// co-resident blocks overlap each other's softmax/staging stalls.
__global__ __launch_bounds__(256, 2) void attn_fwd(const u16* __restrict__ qkv, u16* __restrict__ out){
  const int T = 2048, D3 = 6144, D = 2048, HD = 128;
  const int bh = blockIdx.x;
  const int pr = blockIdx.y;            // 0..15
  const int b = bh >> 4, h = bh & 15;
  const int tid = threadIdx.x, wave = tid >> 6, lane = tid & 63;
  const int lr = lane & 15, lg = lane >> 4;

  __shared__ u16 Klds[64][136];
  __shared__ u16 Vlds[64][136];
  __shared__ u16 Plds[4][16][72];

  const size_t base = (size_t)b * T * D3;
  const unsigned vtr = (unsigned)(uintptr_t)&Vlds[(lane >> 4) * 8 + ((lane >> 2) & 3)][(lane & 3) * 4];

  // staging: 256 thr, 4 sweeps: row = (tid>>4) + 16c, col = (tid&15)*8
  const int srow = tid >> 4;
  const int scol = (tid & 15) * 8;
  const u16* kgp = qkv + base + (size_t)srow * D3 + D + h * HD + scol;
  const u16* vgp = kgp + D;

  for (int half = 0; half < 2; half++){
    const int qt = half ? pr : (31 - pr);   // 64-row subtile, heavy first
    const int q0 = qt * 64;
    const int q0w = q0 + wave * 16;

    short8 qf[4];
    {
      const u16* qrow = qkv + base + (size_t)(q0w + lr) * D3 + h * HD;
      #pragma unroll
      for (int kk = 0; kk < 4; kk++)
        qf[kk] = *(const short8*)(qrow + kk*32 + lg*8);
    }

    f32x4 o[8] = {};
    float mrow[4], lrw[4];
    #pragma unroll
    for (int r = 0; r < 4; r++){ mrow[r] = -1e30f; lrw[r] = 0.f; }

    const int ntiles = qt + 1;
    short8 kreg[4], vreg[4];
    #pragma unroll
    for (int c = 0; c < 4; c++){
      kreg[c] = *(const short8*)(kgp + (size_t)(16 * c) * D3);
      vreg[c] = *(const short8*)(vgp + (size_t)(16 * c) * D3);
    }

    for (int t = 0; t < ntiles; t++){
      const int k0 = t * 64;
      __syncthreads();                       // prior tile's LDS reads done
      #pragma unroll
      for (int c = 0; c < 4; c++){
        *(short8*)&Klds[srow + 16*c][scol] = kreg[c];
        *(short8*)&Vlds[srow + 16*c][scol] = vreg[c];
      }
      __syncthreads();                       // tile staged
      if (t + 1 < ntiles){                   // T14: issue next loads early
        const u16* kn = kgp + (size_t)(k0 + 64) * D3;
        const u16* vn = vgp + (size_t)(k0 + 64) * D3;
        #pragma unroll
        for (int c = 0; c < 4; c++){
          kreg[c] = *(const short8*)(kn + (size_t)(16 * c) * D3);
          vreg[c] = *(const short8*)(vn + (size_t)(16 * c) * D3);
        }
      }

      // ---- S = Q K^T ----
      f32x4 s[4] = {};
      #pragma unroll
      for (int kh = 0; kh < 4; kh++){
        #pragma unroll
        for (int kk = 0; kk < 4; kk++){
          short8 kfrag = *(const short8*)&Klds[kh*16 + lr][kk*32 + lg*8];
          s[kh] = __builtin_amdgcn_mfma_f32_16x16x32_bf16(qf[kk], kfrag, s[kh], 0, 0, 0);
        }
      }
      const float scale = 0.08838834764831845f; // 1/sqrt(128)
      const bool need_mask = (k0 + 63 > q0w);
      #pragma unroll
      for (int kh = 0; kh < 4; kh++){
        int key = k0 + kh*16 + lr;
        #pragma unroll
        for (int r = 0; r < 4; r++){
          float v = s[kh][r] * scale;
          if (need_mask && key > q0w + lg*4 + r) v = -1e30f;
          s[kh][r] = v;
        }
      }
      // ---- online softmax (row = lg*4+r per 16-lane group, col = lr) ----
      float fs[4];
      #pragma unroll
      for (int r = 0; r < 4; r++){
        float mx = fmaxf(fmaxf(s[0][r], s[1][r]), fmaxf(s[2][r], s[3][r]));
        #pragma unroll
        for (int msk = 8; msk >= 1; msk >>= 1)
          mx = fmaxf(mx, __shfl_xor(mx, msk, 64));
        float mnew = fmaxf(mrow[r], mx);
        float f = __expf(mrow[r] - mnew);
        float p0 = __expf(s[0][r] - mnew);
        float p1 = __expf(s[1][r] - mnew);
        float p2 = __expf(s[2][r] - mnew);
        float p3 = __expf(s[3][r] - mnew);
        s[0][r] = p0; s[1][r] = p1; s[2][r] = p2; s[3][r] = p3;
        float rs = (p0 + p1) + (p2 + p3);
        #pragma unroll
        for (int msk = 8; msk >= 1; msk >>= 1)
          rs += __shfl_xor(rs, msk, 64);
        lrw[r] = lrw[r] * f + rs;
        mrow[r] = mnew;
        fs[r] = f;
      }
      #pragma unroll
      for (int dt = 0; dt < 8; dt++)
        #pragma unroll
        for (int r = 0; r < 4; r++)
          o[dt][r] *= fs[r];
      // ---- P -> LDS (bf16) ----
      #pragma unroll
      for (int kh = 0; kh < 4; kh++)
        #pragma unroll
        for (int r = 0; r < 4; r++)
          Plds[wave][lg*4 + r][kh*16 + lr] = f2bf(s[kh][r]);
      asm volatile("s_waitcnt lgkmcnt(0)" ::: "memory");
      __builtin_amdgcn_sched_barrier(0);
      short8 pf[2];
      #pragma unroll
      for (int kp2 = 0; kp2 < 2; kp2++)
        pf[kp2] = *(const short8*)&Plds[wave][lr][kp2*32 + lg*8];
      asm volatile("s_waitcnt lgkmcnt(0)" ::: "memory");
      __builtin_amdgcn_sched_barrier(0);

      // ---- PV with pipelined hardware-transpose V reads ----
      short4v vf[2][2][2];
      #define TR4(BUF, PTR) \
        asm volatile("ds_read_b64_tr_b16 %0, %1"             : "=v"(vf[BUF][0][0]) : "v"(PTR)); \
        asm volatile("ds_read_b64_tr_b16 %0, %1 offset:1088" : "=v"(vf[BUF][0][1]) : "v"(PTR)); \
        asm volatile("ds_read_b64_tr_b16 %0, %1 offset:8704" : "=v"(vf[BUF][1][0]) : "v"(PTR)); \
        asm volatile("ds_read_b64_tr_b16 %0, %1 offset:9792" : "=v"(vf[BUF][1][1]) : "v"(PTR));
      TR4(0, vtr)
      #pragma unroll
      for (int dt = 0; dt < 8; dt++){
        if (dt < 7){
          unsigned pn = vtr + (unsigned)((dt + 1) * 32);
          TR4((dt + 1) & 1, pn)
          asm volatile("s_waitcnt lgkmcnt(4)" ::: "memory");
        } else {
          asm volatile("s_waitcnt lgkmcnt(0)" ::: "memory");
        }
        __builtin_amdgcn_sched_barrier(0);
        short8 v0 = cat8(vf[dt & 1][0][0], vf[dt & 1][0][1]);
        short8 v1 = cat8(vf[dt & 1][1][0], vf[dt & 1][1][1]);
        o[dt] = __builtin_amdgcn_mfma_f32_16x16x32_bf16(pf[0], v0, o[dt], 0, 0, 0);
        o[dt] = __builtin_amdgcn_mfma_f32_16x16x32_bf16(pf[1], v1, o[dt], 0, 0, 0);
      }
      #undef TR4
    }
    // ---- epilogue for this half ----
    float rl[4];
    #pragma unroll
    for (int r = 0; r < 4; r++) rl[r] = 1.0f / lrw[r];
    #pragma unroll
    for (int dt = 0; dt < 8; dt++){
      #pragma unroll
      for (int r = 0; r < 4; r++){
        float v = o[dt][r] * rl[r];
        int qa = q0w + lg*4 + r;
        out[(size_t)(b * T + qa) * D + h * HD + dt*16 + lr] = f2bf(v);
      }
    }
  }
}

extern "C" void kernel_launch(void* const* d_in, const int* in_sizes, int n_in,
                              void* d_out, int out_size, void* d_ws, size_t ws_size,
                              hipStream_t stream) {
  const float* x    = (const float*)d_in[0];   // [2,2048,2048]
  const float* wqkv = (const float*)d_in[1];   // [6144,2048]
  const float* wout = (const float*)d_in[2];   // [2048,2048]
  float* out = (float*)d_out;                  // [2,2048,2048] f32

  u16* ws    = (u16*)d_ws;
  u16* xb    = ws;                    //  8,388,608 elems
  u16* wqkvb = xb + 8388608;          // 12,582,912 elems
  u16* qkvb  = wqkvb + 12582912;      // 25,165,824 elems
  u16* attnb = xb;                    // alias: x dead after GEMM1
  u16* woutb = wqkvb;                 // alias: wqkv dead after GEMM1

  cvt_bf16<<<2048, 256, 0, stream>>>(x,    xb,    8388608 / 4);
  cvt_bf16<<<2048, 256, 0, stream>>>(wqkv, wqkvb, 12582912 / 4);

  // qkv = x @ Wqkv^T : [4096][6144] bf16  (128^2 m97, 32x48 = 1536 blocks)
  gemm_bt<1><<<dim3(32, 48), 256, 0, stream>>>(xb, wqkvb, qkvb, 4096, 6144, 2048);

  cvt_bf16<<<2048, 256, 0, stream>>>(wout, woutb, 4194304 / 4);

  // attention: [4096][2048] bf16  (512 blocks = 2 blocks/CU)
  attn_fwd<<<dim3(32, 16), 256, 0, stream>>>(qkvb, attnb);

  // y = attn @ Wout^T : [4096][2048] f32  (32x16 = 512 blocks)
  gemm_bt<0><<<dim3(32, 16), 256, 0, stream>>>(attnb, woutb, out, 4096, 2048, 2048);
}

// Round 9
// 282.050 us; speedup vs baseline: 1.1575x; 1.0403x over previous
//
#include <hip/hip_runtime.h>

typedef short short8 __attribute__((ext_vector_type(8)));
typedef short short4v __attribute__((ext_vector_type(4)));
typedef float f32x4 __attribute__((ext_vector_type(4)));
typedef unsigned short u16;
typedef u16 ushort4v __attribute__((ext_vector_type(4)));

__device__ inline u16 f2bf(float f){
  unsigned int u = __builtin_bit_cast(unsigned int, f);
  u = (u + 0x7fffu + ((u >> 16) & 1u)) >> 16;
  return (u16)u;
}

__device__ inline short8 cat8(short4v a, short4v b){
  short8 r;
  r[0]=a[0]; r[1]=a[1]; r[2]=a[2]; r[3]=a[3];
  r[4]=b[0]; r[5]=b[1]; r[6]=b[2]; r[7]=b[3];
  return r;
}

// async global->LDS, 16B per lane. lds dest = wave-uniform base + lane*16.
__device__ inline void gload_lds16(const void* g, unsigned lds_addr){
  __builtin_amdgcn_global_load_lds((__attribute__((address_space(1))) void*)(uintptr_t)g,
                                   (__attribute__((address_space(3))) void*)(uintptr_t)lds_addr,
                                   16, 0, 0);
}

// ---------------- f32 -> bf16 convert (vectorized) ----------------
__global__ void cvt_bf16(const float* __restrict__ in, u16* __restrict__ out, int n4){
  int stride = gridDim.x * blockDim.x;
  for (int i = blockIdx.x * blockDim.x + threadIdx.x; i < n4; i += stride){
    float4 v = ((const float4*)in)[i];
    ushort4v r = { f2bf(v.x), f2bf(v.y), f2bf(v.z), f2bf(v.w) };
    ((ushort4v*)out)[i] = r;
  }
}

// ---------------- bf16 GEMM: C[M][N] = A[M][K] * B[N][K]^T ----------------
// m97 structure (r4 champion, 862 TF, no XCD swizzle — measured: swizzle
// doubled FETCH_SIZE): 128x128, BK=64, 256 thr, global_load_lds(16B),
// XOR-swizzled source+read (0 bank conflicts), co-residency pipelines.
template<int OUT_BF16>
__global__ __launch_bounds__(256) void gemm_bt(const u16* __restrict__ A, const u16* __restrict__ B,
                                               void* __restrict__ Cv, int M, int N, int K){
  __shared__ u16 As[128 * 64];
  __shared__ u16 Bs[128 * 64];
  const int tid  = threadIdx.x;
  const int wave = tid >> 6, lane = tid & 63;
  const int lr = lane & 15, lg = lane >> 4;
  const int wm = wave >> 1, wn = wave & 1;
  const long bm = blockIdx.x * 128L, bn = blockIdx.y * 128L;
  const unsigned asb = (unsigned)(uintptr_t)As;
  const unsigned bsb = (unsigned)(uintptr_t)Bs;

  const int  srow = wave * 32 + (lane >> 3);
  const int  scol = ((lane & 7) ^ (lane >> 3)) * 8;
  const u16* aptr = A + (bm + srow) * (long)K + scol;
  const u16* bptr = B + (bn + srow) * (long)K + scol;
  const unsigned sdst = (unsigned)(wave * 4096);

  f32x4 acc[4][4] = {};
  for (int k0 = 0; k0 < K; k0 += 64){
    #pragma unroll
    for (int c = 0; c < 4; c++){
      gload_lds16(aptr + (size_t)(8 * c) * K + k0, asb + sdst + 1024u * c);
      gload_lds16(bptr + (size_t)(8 * c) * K + k0, bsb + sdst + 1024u * c);
    }
    __syncthreads();
    #pragma unroll
    for (int kk = 0; kk < 2; kk++){
      short8 af[4], bfr[4];
      #pragma unroll
      for (int m = 0; m < 4; m++){
        int row = wm * 64 + m * 16 + lr;
        int phys = (kk * 4 + lg) ^ (row & 7);
        af[m] = *(const short8*)&As[row * 64 + phys * 8];
      }
      #pragma unroll
      for (int n = 0; n < 4; n++){
        int row = wn * 64 + n * 16 + lr;
        int phys = (kk * 4 + lg) ^ (row & 7);
        bfr[n] = *(const short8*)&Bs[row * 64 + phys * 8];
      }
      #pragma unroll
      for (int m = 0; m < 4; m++)
        #pragma unroll
        for (int n = 0; n < 4; n++)
          acc[m][n] = __builtin_amdgcn_mfma_f32_16x16x32_bf16(af[m], bfr[n], acc[m][n], 0, 0, 0);
    }
    __syncthreads();
  }
  #pragma unroll
  for (int m = 0; m < 4; m++){
    #pragma unroll
    for (int n = 0; n < 4; n++){
      #pragma unroll
      for (int r = 0; r < 4; r++){
        long row = bm + wm*64 + m*16 + lg*4 + r;
        long col = bn + wn*64 + n*16 + lr;
        float v = acc[m][n][r];
        if (OUT_BF16) ((u16*)Cv)[row * (long)N + col] = f2bf(v);
        else          ((float*)Cv)[row * (long)N + col] = v;
      }
    }
  }
}

// ---------------- causal flash attention ----------------
// 256 thr = 4 waves x 16 q-rows. Block (bh, p) owns TWO 64-row q-subtiles:
// heavy H=31-p and light L=p (L<H so light's KV range is a prefix of
// heavy's) -> each KV tile staged ONCE, consumed by both while t<=L.
// Grid 32x16 = 512 blocks = 2 blocks/CU (LDS 44KB). log2-domain softmax
// with defer-max (T13).
__global__ __launch_bounds__(256, 2) void attn_fwd(const u16* __restrict__ qkv, u16* __restrict__ out){
  const int T = 2048, D3 = 6144, D = 2048, HD = 128;
  const int bh = blockIdx.x;
  const int p = blockIdx.y;            // 0..15
  const int b = bh >> 4, h = bh & 15;
  const int tid = threadIdx.x, wave = tid >> 6, lane = tid & 63;
  const int lr = lane & 15, lg = lane >> 4;

  __shared__ u16 Klds[64][136];
  __shared__ u16 Vlds[64][136];
  __shared__ u16 Plds[4][16][72];

  const size_t base = (size_t)b * T * D3;
  const unsigned vtr = (unsigned)(uintptr_t)&Vlds[(lane >> 4) * 8 + ((lane >> 2) & 3)][(lane & 3) * 4];

  const int srow = tid >> 4;
  const int scol = (tid & 15) * 8;
  const u16* kgp = qkv + base + (size_t)srow * D3 + D + h * HD + scol;
  const u16* vgp = kgp + D;

  const int H = 31 - p, L = p;
  const int q0A = H * 64 + wave * 16;
  const int q0B = L * 64 + wave * 16;

  short8 qfA[4], qfB[4];
  {
    const u16* qa = qkv + base + (size_t)(q0A + lr) * D3 + h * HD;
    const u16* qb = qkv + base + (size_t)(q0B + lr) * D3 + h * HD;
    #pragma unroll
    for (int kk = 0; kk < 4; kk++){
      qfA[kk] = *(const short8*)(qa + kk*32 + lg*8);
      qfB[kk] = *(const short8*)(qb + kk*32 + lg*8);
    }
  }

  f32x4 oA[8] = {}, oB[8] = {};
  float mA[4], lA[4], mB[4], lB[4];
  #pragma unroll
  for (int r = 0; r < 4; r++){ mA[r] = -1e30f; lA[r] = 0.f; mB[r] = -1e30f; lB[r] = 0.f; }

  // log2-domain scale: 1/sqrt(128) * log2(e)
  const float scale2 = 0.12751971252971732f;
  const float THR = 11.5f;   // defer-max threshold (8 nats in log2 units)

  // one softmax+PV pass for a 16-row q-state against the staged 64-key tile
  #define PROCESS(QF, O, MR, LW, Q0W, K0) { \
    f32x4 s[4] = {}; \
    _Pragma("unroll") \
    for (int kh = 0; kh < 4; kh++){ \
      _Pragma("unroll") \
      for (int kk = 0; kk < 4; kk++){ \
        short8 kfrag = *(const short8*)&Klds[kh*16 + lr][kk*32 + lg*8]; \
        s[kh] = __builtin_amdgcn_mfma_f32_16x16x32_bf16(QF[kk], kfrag, s[kh], 0, 0, 0); \
      } \
    } \
    const bool need_mask = ((K0) + 63 > (Q0W)); \
    _Pragma("unroll") \
    for (int kh = 0; kh < 4; kh++){ \
      int key = (K0) + kh*16 + lr; \
      _Pragma("unroll") \
      for (int r = 0; r < 4; r++){ \
        float v = s[kh][r] * scale2; \
        if (need_mask && key > (Q0W) + lg*4 + r) v = -1e30f; \
        s[kh][r] = v; \
      } \
    } \
    float mx[4]; \
    _Pragma("unroll") \
    for (int r = 0; r < 4; r++){ \
      float m0 = fmaxf(fmaxf(s[0][r], s[1][r]), fmaxf(s[2][r], s[3][r])); \
      _Pragma("unroll") \
      for (int msk = 8; msk >= 1; msk >>= 1) m0 = fmaxf(m0, __shfl_xor(m0, msk, 64)); \
      mx[r] = m0; \
    } \
    bool cnd = (mx[0] <= MR[0] + THR) && (mx[1] <= MR[1] + THR) && \
               (mx[2] <= MR[2] + THR) && (mx[3] <= MR[3] + THR); \
    if (__all(cnd)){ \
      _Pragma("unroll") \
      for (int r = 0; r < 4; r++){ \
        float p0 = exp2f(s[0][r] - MR[r]); \
        float p1 = exp2f(s[1][r] - MR[r]); \
        float p2 = exp2f(s[2][r] - MR[r]); \
        float p3 = exp2f(s[3][r] - MR[r]); \
        s[0][r] = p0; s[1][r] = p1; s[2][r] = p2; s[3][r] = p3; \
        float rs = (p0 + p1) + (p2 + p3); \
        _Pragma("unroll") \
        for (int msk = 8; msk >= 1; msk >>= 1) rs += __shfl_xor(rs, msk, 64); \
        LW[r] += rs; \
      } \
    } else { \
      float fs[4]; \
      _Pragma("unroll") \
      for (int r = 0; r < 4; r++){ \
        float mnew = fmaxf(MR[r], mx[r]); \
        float f = exp2f(MR[r] - mnew); \
        float p0 = exp2f(s[0][r] - mnew); \
        float p1 = exp2f(s[1][r] - mnew); \
        float p2 = exp2f(s[2][r] - mnew); \
        float p3 = exp2f(s[3][r] - mnew); \
        s[0][r] = p0; s[1][r] = p1; s[2][r] = p2; s[3][r] = p3; \
        float rs = (p0 + p1) + (p2 + p3); \
        _Pragma("unroll") \
        for (int msk = 8; msk >= 1; msk >>= 1) rs += __shfl_xor(rs, msk, 64); \
        LW[r] = LW[r] * f + rs; \
        MR[r] = mnew; \
        fs[r] = f; \
      } \
      _Pragma("unroll") \
      for (int dt = 0; dt < 8; dt++) \
        _Pragma("unroll") \
        for (int r = 0; r < 4; r++) O[dt][r] *= fs[r]; \
    } \
    _Pragma("unroll") \
    for (int kh = 0; kh < 4; kh++) \
      _Pragma("unroll") \
      for (int r = 0; r < 4; r++) \
        Plds[wave][lg*4 + r][kh*16 + lr] = f2bf(s[kh][r]); \
    asm volatile("s_waitcnt lgkmcnt(0)" ::: "memory"); \
    __builtin_amdgcn_sched_barrier(0); \
    short8 pf[2]; \
    _Pragma("unroll") \
    for (int kp2 = 0; kp2 < 2; kp2++) \
      pf[kp2] = *(const short8*)&Plds[wave][lr][kp2*32 + lg*8]; \
    asm volatile("s_waitcnt lgkmcnt(0)" ::: "memory"); \
    __builtin_amdgcn_sched_barrier(0); \
    short4v vf[2][2][2]; \
    asm volatile("ds_read_b64_tr_b16 %0, %1"             : "=v"(vf[0][0][0]) : "v"(vtr)); \
    asm volatile("ds_read_b64_tr_b16 %0, %1 offset:1088" : "=v"(vf[0][0][1]) : "v"(vtr)); \
    asm volatile("ds_read_b64_tr_b16 %0, %1 offset:8704" : "=v"(vf[0][1][0]) : "v"(vtr)); \
    asm volatile("ds_read_b64_tr_b16 %0, %1 offset:9792" : "=v"(vf[0][1][1]) : "v"(vtr)); \
    _Pragma("unroll") \
    for (int dt = 0; dt < 8; dt++){ \
      if (dt < 7){ \
        unsigned pn = vtr + (unsigned)((dt + 1) * 32); \
        int bnx = (dt + 1) & 1; \
        asm volatile("ds_read_b64_tr_b16 %0, %1"             : "=v"(vf[bnx][0][0]) : "v"(pn)); \
        asm volatile("ds_read_b64_tr_b16 %0, %1 offset:1088" : "=v"(vf[bnx][0][1]) : "v"(pn)); \
        asm volatile("ds_read_b64_tr_b16 %0, %1 offset:8704" : "=v"(vf[bnx][1][0]) : "v"(pn)); \
        asm volatile("ds_read_b64_tr_b16 %0, %1 offset:9792" : "=v"(vf[bnx][1][1]) : "v"(pn)); \
        asm volatile("s_waitcnt lgkmcnt(4)" ::: "memory"); \
      } else { \
        asm volatile("s_waitcnt lgkmcnt(0)" ::: "memory"); \
      } \
      __builtin_amdgcn_sched_barrier(0); \
      short8 v0 = cat8(vf[dt & 1][0][0], vf[dt & 1][0][1]); \
      short8 v1 = cat8(vf[dt & 1][1][0], vf[dt & 1][1][1]); \
      O[dt] = __builtin_amdgcn_mfma_f32_16x16x32_bf16(pf[0], v0, O[dt], 0, 0, 0); \
      O[dt] = __builtin_amdgcn_mfma_f32_16x16x32_bf16(pf[1], v1, O[dt], 0, 0, 0); \
    } \
  }

  const int ntiles = H + 1;
  short8 kreg[4], vreg[4];
  #pragma unroll
  for (int c = 0; c < 4; c++){
    kreg[c] = *(const short8*)(kgp + (size_t)(16 * c) * D3);
    vreg[c] = *(const short8*)(vgp + (size_t)(16 * c) * D3);
  }

  for (int t = 0; t < ntiles; t++){
    const int k0 = t * 64;
    __syncthreads();                       // prior tile's LDS reads done
    #pragma unroll
    for (int c = 0; c < 4; c++){
      *(short8*)&Klds[srow + 16*c][scol] = kreg[c];
      *(short8*)&Vlds[srow + 16*c][scol] = vreg[c];
    }
    __syncthreads();                       // tile staged
    if (t + 1 < ntiles){                   // T14: issue next loads early
      const u16* kn = kgp + (size_t)(k0 + 64) * D3;
      const u16* vn = vgp + (size_t)(k0 + 64) * D3;
      #pragma unroll
      for (int c = 0; c < 4; c++){
        kreg[c] = *(const short8*)(kn + (size_t)(16 * c) * D3);
        vreg[c] = *(const short8*)(vn + (size_t)(16 * c) * D3);
      }
    }

    PROCESS(qfA, oA, mA, lA, q0A, k0)        // heavy state: every tile
    if (t <= L){
      PROCESS(qfB, oB, mB, lB, q0B, k0)      // light state: shared prefix
    }
  }
  #undef PROCESS

  // ---- epilogues ----
  #pragma unroll
  for (int r = 0; r < 4; r++){ lA[r] = 1.0f / lA[r]; lB[r] = 1.0f / lB[r]; }
  #pragma unroll
  for (int dt = 0; dt < 8; dt++){
    #pragma unroll
    for (int r = 0; r < 4; r++){
      int qa = q0A + lg*4 + r;
      out[(size_t)(b * T + qa) * D + h * HD + dt*16 + lr] = f2bf(oA[dt][r] * lA[r]);
      int qb = q0B + lg*4 + r;
      out[(size_t)(b * T + qb) * D + h * HD + dt*16 + lr] = f2bf(oB[dt][r] * lB[r]);
    }
  }
}

extern "C" void kernel_launch(void* const* d_in, const int* in_sizes, int n_in,
                              void* d_out, int out_size, void* d_ws, size_t ws_size,
                              hipStream_t stream) {
  const float* x    = (const float*)d_in[0];   // [2,2048,2048]
  const float* wqkv = (const float*)d_in[1];   // [6144,2048]
  const float* wout = (const float*)d_in[2];   // [2048,2048]
  float* out = (float*)d_out;                  // [2,2048,2048] f32

  u16* ws    = (u16*)d_ws;
  u16* xb    = ws;                    //  8,388,608 elems
  u16* wqkvb = xb + 8388608;          // 12,582,912 elems
  u16* qkvb  = wqkvb + 12582912;      // 25,165,824 elems
  u16* attnb = xb;                    // alias: x dead after GEMM1
  u16* woutb = wqkvb;                 // alias: wqkv dead after GEMM1

  cvt_bf16<<<2048, 256, 0, stream>>>(x,    xb,    8388608 / 4);
  cvt_bf16<<<2048, 256, 0, stream>>>(wqkv, wqkvb, 12582912 / 4);

  // qkv = x @ Wqkv^T : [4096][6144] bf16  (128^2 m97, 32x48 = 1536 blocks)
  gemm_bt<1><<<dim3(32, 48), 256, 0, stream>>>(xb, wqkvb, qkvb, 4096, 6144, 2048);

  cvt_bf16<<<2048, 256, 0, stream>>>(wout, woutb, 4194304 / 4);

  // attention: [4096][2048] bf16  (512 blocks = 2 blocks/CU)
  attn_fwd<<<dim3(32, 16), 256, 0, stream>>>(qkvb, attnb);

  // y = attn @ Wout^T : [4096][2048] f32  (32x16 = 512 blocks)
  gemm_bt<0><<<dim3(32, 16), 256, 0, stream>>>(attnb, woutb, out, 4096, 2048, 2048);
}